// Round 3
// baseline (26051.886 us; speedup 1.0000x reference)
//
#include <hip/hip_runtime.h>

// ============================================================================
// Two-level LSTM (char k-mer LSTM -> word LSTM), MI355X.
//
// Persistent multi-WG recurrence kernels, all worker WGs elected onto ONE XCD
// (pigeonhole election, HW_REG_XCC_ID).
//
// R10 changes over R9 (protocol semantics unchanged, latency-chain attack):
//  1. Weight residency: amdgpu_waves_per_eu(1,1) char / (2,2) word. R9 showed
//     VGPR_Count=56 -- wreg[16] (64 VGPRs) was re-materialized from memory
//     every step (the poll asm's "memory" clobber forbids caching the loads
//     unless the values live in registers). Diagnostic: VGPR_Count >= 130.
//  2. 2-deep pipelined poll: two sc1 loads in flight, s_waitcnt vmcnt(1)
//     alternating -> discovery quantum ~300cy -> ~150cy. Hazard fix per the
//     hoist-past-inline-asm-waitcnt trap: the waitcnt asm TIES the polled
//     register ("+v") so the tag compare cannot be scheduled before the wait;
//     sched_barrier(0) as belt-and-braces. sc1 = device scope on gfx940+
//     (SC field: 0=CU,1=SE,2=Device,3=System; R8's sc0 hang was SE scope).
//  3. Publish via __hip_atomic_store(RELAXED, AGENT) (device-scope
//     write-through store) instead of swap-RMW: removes the TCC RMW pipeline
//     from the commit path. Tag+data still one 8-byte word.
//  4. Prefetch reorder: tab[ch] ds_read hoisted before the poll (off the
//     producer-tail critical path); char_ids[t+1] and Xw[t+1] issued after
//     the poll so poll-entry vmcnt(0) does not pay their latency.
//
// Race-freedom (R4 argument, unchanged): WG g publishes tag t+1 only after
// all its threads passed the post-poll barrier of step t. Every WG
// collectively polls ALL producers' slots each step; a producer publishing
// tag t+1 therefore implies every WG completed its step-t poll, so
// overwriting the same-parity tag-(t-1) slot is safe. Same-lane same-address
// publishes (t, t+2) are ordered because the intervening step-t+1 poll waits
// vmcnt, and vmcnt retires vector-memory ops (loads AND stores) in order.
// Stale slots from a previous run hold tags {16383,16384}/{4095,4096}; a
// fresh run's first write to each slot (tags 1,2) lands before any poll
// could expect a tag that collides with the stale ones -> no false positive.
// ============================================================================

#define S_LEN 4096
#define TCH   16384
#define ALPHA 25
#define ECH   64
#define HR    256
#define DL    128
#define EW    128
#define HW    512
#define NWC   16           // char worker WGs (16 units each)
#define GRIDC 128
#define NWW   32           // word worker WGs (16 units each)
#define GRIDW 256

static __device__ __forceinline__ float fsigmoid(float x) {
  x = fminf(fmaxf(x, -30.f), 30.f);
  return __builtin_amdgcn_rcpf(1.0f + __expf(-x));
}
static __device__ __forceinline__ float ftanh(float x) {
  x = fminf(fmaxf(x, -15.f), 15.f);
  float e = __expf(2.0f * x);
  return 1.0f - 2.0f * __builtin_amdgcn_rcpf(e + 1.0f);
}

static __device__ __forceinline__ void barrier_lds() {
  asm volatile("s_waitcnt lgkmcnt(0)\n\ts_barrier" ::: "memory");
}

// 2-deep pipelined coherent poll. sc1 load = device-scope (bypasses L0/L1,
// served by the XCD's L2 -- the commit point of the publish stores).
// Entry vmcnt(0) cleans the counter so vmcnt(1) waits target OUR loads.
// The waitcnt asm ties the polled register so the compare can't be hoisted.
static __device__ __forceinline__ unsigned long long poll2(
    const unsigned long long* p, unsigned tgt) {
  unsigned long long a, b;
  asm volatile("s_waitcnt vmcnt(0)" ::: "memory");
  asm volatile("global_load_dwordx2 %0, %1, off sc1"
               : "=v"(a) : "v"(p) : "memory");
  for (;;) {
    asm volatile("global_load_dwordx2 %0, %1, off sc1"
                 : "=v"(b) : "v"(p) : "memory");
    asm volatile("s_waitcnt vmcnt(1)" : "+v"(a) :: "memory");
    __builtin_amdgcn_sched_barrier(0);
    if ((unsigned)(a >> 32) == tgt) break;
    asm volatile("global_load_dwordx2 %0, %1, off sc1"
                 : "=v"(a) : "v"(p) : "memory");
    asm volatile("s_waitcnt vmcnt(1)" : "+v"(b) :: "memory");
    __builtin_amdgcn_sched_barrier(0);
    if ((unsigned)(b >> 32) == tgt) { a = b; break; }
  }
  asm volatile("s_waitcnt vmcnt(0)" ::: "memory");  // drain dangling load
  return a;
}
// Publish: device-scope atomic store (write-through to L2), fire-and-forget.
static __device__ __forceinline__ void publish(
    unsigned long long* p, unsigned long long v) {
  __hip_atomic_store(p, v, __ATOMIC_RELAXED, __HIP_MEMORY_SCOPE_AGENT);
}

// Deadlock-free single-XCD role election (R4-proven).
static __device__ __forceinline__ int elect_role(int* el, int NW) {
  unsigned xcd;
  asm volatile("s_getreg_b32 %0, hwreg(HW_REG_XCC_ID)" : "=s"(xcd));
  xcd &= 7u;
  int r = __hip_atomic_fetch_add(&el[xcd], 1, __ATOMIC_RELAXED,
                                 __HIP_MEMORY_SCOPE_AGENT);
  if (r == NW - 1) {
    int exp = -1;
    __hip_atomic_compare_exchange_strong(&el[8], &exp, (int)xcd,
        __ATOMIC_RELAXED, __ATOMIC_RELAXED, __HIP_MEMORY_SCOPE_AGENT);
  }
  int w;
  while ((w = __hip_atomic_load(&el[8], __ATOMIC_RELAXED,
                                __HIP_MEMORY_SCOPE_AGENT)) < 0) {}
  if (w != (int)xcd) return -1;
  int rr = __hip_atomic_fetch_add(&el[9], 1, __ATOMIC_RELAXED,
                                  __HIP_MEMORY_SCOPE_AGENT);
  return (rr < NW) ? rr : -1;
}

__global__ void k_init(int* ec, int* ew) {
  int t = threadIdx.x;
  if (t < 10) ec[t] = (t == 8) ? -1 : 0;
  else if (t < 20) { int u = t - 10; ew[u] = (u == 8) ? -1 : 0; }
}

// ---------------------------------------------------------------------------
// K1a: char gate-input table: table[a][row] = b_r[row] + E_char[a,:]·W_ih_r[row,:]
// ---------------------------------------------------------------------------
__global__ void k_table(const float* __restrict__ Ec, const float* __restrict__ Wih,
                        const float* __restrict__ br, float* __restrict__ table) {
  __shared__ __align__(16) float e[ECH];
  int a = blockIdx.x, tid = threadIdx.x;
  if (tid < ECH) e[tid] = Ec[a * ECH + tid];
  __syncthreads();
  for (int row = tid; row < 4 * HR; row += 256) {
    const float4* w = (const float4*)(Wih + row * ECH);
    const float4* e4 = (const float4*)e;
    float acc = 0.f;
#pragma unroll
    for (int j = 0; j < ECH / 4; ++j) {
      float4 wv = w[j], ev = e4[j];
      acc += wv.x * ev.x + wv.y * ev.y + wv.z * ev.z + wv.w * ev.w;
    }
    table[a * (4 * HR) + row] = acc + br[row];
  }
}

// ---------------------------------------------------------------------------
// K1b: permute W_ih_w k-major: WT[k][p], p = wg*64 + (gate*16 + unit).
// ---------------------------------------------------------------------------
__global__ void k_permw(const float* __restrict__ Wihw, const float* __restrict__ bw,
                        float* __restrict__ WT, float* __restrict__ bperm) {
  int e = blockIdx.x * 256 + threadIdx.x;
  int p = e >> 8, k = e & 255;
  int r = p & 63, wgp = p >> 6;
  int R = (r >> 4) * HW + wgp * 16 + (r & 15);
  WT[k * (4 * HW) + p] = Wihw[R * (EW + DL) + k];
  if (k == 0) bperm[p] = bw[R];
}

// ---------------------------------------------------------------------------
// K2: persistent char LSTM. 16 WGs x 256 threads on one XCD.
// slots: SINGLE copy, [parity][element 0..255], 8 B tagged words.
// ---------------------------------------------------------------------------
__global__ __attribute__((amdgpu_flat_work_group_size(256, 256),
                          amdgpu_waves_per_eu(1, 1)))
void k_char_lstm(
    const int* __restrict__ char_ids, const float* __restrict__ Whh,
    const float* __restrict__ table, unsigned long long* __restrict__ slots,
    int* __restrict__ elect, float* __restrict__ h_word)
{
  __shared__ int role_sh;
  if (threadIdx.x == 0) role_sh = elect_role(elect, NWC);
  __syncthreads();
  const int wg = role_sh;
  if (wg < 0) return;

  const int tid = threadIdx.x;
  const int wave = tid >> 6, lane = tid & 63;
  const int R = (lane >> 4) * HR + wg * 16 + (lane & 15);
  float4 wreg[16];
  {
    const float4* wp = (const float4*)(Whh + R * HR + wave * 64);
#pragma unroll
    for (int j = 0; j < 16; ++j) wreg[j] = wp[j];
  }
  __shared__ __align__(16) float tab[ALPHA * 64];
  __shared__ __align__(16) float hst[4][64];
  __shared__ __align__(16) float part[2][4][64];
  for (int i = tid; i < ALPHA * 64; i += 256) {
    int chh = i >> 6, r = i & 63;
    int Rr = (r >> 4) * HR + wg * 16 + (r & 15);
    tab[i] = table[chh * (4 * HR) + Rr];
  }
  hst[wave][lane] = 0.f;
  float creg = 0.f;                      // cell state: wave0 lanes<16
  __syncthreads();
  int ch = char_ids[0];

#pragma unroll 1
  for (int t = 0; t < TCH; ++t) {
    // tab row for THIS step: ds_read issued before the poll, consumed in the
    // tail -> its ~120cy latency hides under the poll wait.
    float tabv = 0.f;
    if (wave == 0) tabv = tab[ch * 64 + lane];
    if (t > 0) {
      const unsigned long long* sl = slots + ((t - 1) & 1) * HR + tid;
      unsigned long long v = poll2(sl, (unsigned)t);
      hst[wave][lane] = __uint_as_float((unsigned)v);
      // same-wave LDS write->read: compiler-inserted lgkmcnt, no barrier.
    }
    int chn = (t + 1 < TCH) ? char_ids[t + 1] : 0;   // next char, off-path
    const float4* hp = (const float4*)hst[wave];
    float a0 = 0.f, a1 = 0.f, a2 = 0.f, a3 = 0.f;
#pragma unroll
    for (int j = 0; j < 4; ++j) {
      float4 h0 = hp[4*j+0], h1 = hp[4*j+1], h2 = hp[4*j+2], h3 = hp[4*j+3];
      float4 w0 = wreg[4*j+0], w1 = wreg[4*j+1], w2 = wreg[4*j+2], w3 = wreg[4*j+3];
      a0 += w0.x*h0.x + w0.y*h0.y + w0.z*h0.z + w0.w*h0.w;
      a1 += w1.x*h1.x + w1.y*h1.y + w1.z*h1.z + w1.w*h1.w;
      a2 += w2.x*h2.x + w2.y*h2.y + w2.z*h2.z + w2.w*h2.w;
      a3 += w3.x*h3.x + w3.y*h3.y + w3.z*h3.z + w3.w*h3.w;
    }
    const int par = t & 1;
    part[par][wave][lane] = (a0 + a1) + (a2 + a3);
    barrier_lds();                       // single barrier per step
    if (wave == 0) {
      float z = ((part[par][0][lane] + part[par][1][lane]) +
                 (part[par][2][lane] + part[par][3][lane])) + tabv;
      int u = lane & 15;
      float zi = __shfl(z, u,      64);
      float zf = __shfl(z, u + 16, 64);
      float zg = __shfl(z, u + 32, 64);
      float zo = __shfl(z, u + 48, 64);
      if (lane < 16) {
        float ig = fsigmoid(zi), fg = fsigmoid(zf), og = fsigmoid(zo);
        float gg = ftanh(zg);
        creg = fg * creg + ig * gg;
        float h = og * ftanh(creg);
        unsigned long long pv =
            (((unsigned long long)(unsigned)(t + 1)) << 32) |
            (unsigned long long)__float_as_uint(h);
        publish(slots + par * HR + wg * 16 + lane, pv);
        if ((t & 3) == 3)
          h_word[(t >> 2) * HR + wg * 16 + lane] = h;
      }
    }
    ch = chn;
  }
}

// ---------------------------------------------------------------------------
// K3a: latent = tanh(h_word @ W_lat^T + b_lat).
// ---------------------------------------------------------------------------
__global__ __launch_bounds__(128) void k_latent(
    const float* __restrict__ hw, const float* __restrict__ Wlat,
    const float* __restrict__ blat, float* __restrict__ lat)
{
  int t = blockIdx.x, d = threadIdx.x;
  __shared__ __align__(16) float hh[HR];
  ((float2*)hh)[d] = ((const float2*)(hw + t * HR))[d];
  __syncthreads();
  const float4* w = (const float4*)(Wlat + d * HR);
  const float4* h4 = (const float4*)hh;
  float acc = 0.f;
#pragma unroll 8
  for (int j = 0; j < HR / 4; ++j) {
    float4 wv = w[j], hv = h4[j];
    acc += wv.x * hv.x + wv.y * hv.y + wv.z * hv.z + wv.w * hv.w;
  }
  lat[t * DL + d] = tanhf(acc + blat[d]);
}

// ---------------------------------------------------------------------------
// K3b: Xw[t][p] = bperm[p] + concat(E_word[wid[t]], latent[t]) · W row(p)
// ---------------------------------------------------------------------------
__global__ __launch_bounds__(256) void k_xw(
    const float* __restrict__ Ew, const int* __restrict__ wid,
    const float* __restrict__ lat, const float* __restrict__ WT,
    const float* __restrict__ bperm, float* __restrict__ Xw)
{
  int tblk = blockIdx.x, pblk = blockIdx.y;
  int tid = threadIdx.x;
  int p = pblk * 256 + tid;
  __shared__ __align__(16) float xt[32][256];
  int t0 = tblk * 32;
  for (int i = tid; i < 32 * 256; i += 256) {
    int tl = i >> 8, e = i & 255;
    int t = t0 + tl;
    float v;
    if (e < 128) v = Ew[wid[t] * EW + e];
    else         v = lat[t * DL + (e - 128)];
    xt[tl][e] = v;
  }
  __syncthreads();
  float acc[32];
#pragma unroll
  for (int i = 0; i < 32; ++i) acc[i] = 0.f;
  for (int k = 0; k < 256; k += 4) {
    float w0 = WT[(k + 0) * (4 * HW) + p];
    float w1 = WT[(k + 1) * (4 * HW) + p];
    float w2 = WT[(k + 2) * (4 * HW) + p];
    float w3 = WT[(k + 3) * (4 * HW) + p];
#pragma unroll
    for (int tl = 0; tl < 32; ++tl) {
      float4 x4 = *(const float4*)&xt[tl][k];
      acc[tl] += w0 * x4.x + w1 * x4.y + w2 * x4.z + w3 * x4.w;
    }
  }
  float b = bperm[p];
#pragma unroll
  for (int tl = 0; tl < 32; ++tl)
    Xw[(t0 + tl) * (4 * HW) + p] = acc[tl] + b;
}

// ---------------------------------------------------------------------------
// K4: persistent word LSTM. 32 WGs x 512 threads (8 waves) on one XCD.
// Wave w = k-segment [64w, 64w+64); lane: gate=lane>>4, unit=lane&15.
// slots: SINGLE copy, [parity][element 0..511], 8 B tagged words.
// ---------------------------------------------------------------------------
__global__ __attribute__((amdgpu_flat_work_group_size(512, 512),
                          amdgpu_waves_per_eu(2, 2)))
void k_word_lstm(
    const float* __restrict__ Whh, const float* __restrict__ Xw,
    unsigned long long* __restrict__ slots, int* __restrict__ elect,
    float* __restrict__ out)
{
  __shared__ int role_sh;
  if (threadIdx.x == 0) role_sh = elect_role(elect, NWW);
  __syncthreads();
  const int wg = role_sh;
  if (wg < 0) return;

  const int tid = threadIdx.x;
  const int wave = tid >> 6, lane = tid & 63;
  const int R = (lane >> 4) * HW + wg * 16 + (lane & 15);
  float4 wreg[16];
  {
    const float4* wp = (const float4*)(Whh + R * HW + wave * 64);
#pragma unroll
    for (int j = 0; j < 16; ++j) wreg[j] = wp[j];
  }
  __shared__ __align__(16) float hst[8][64];
  __shared__ __align__(16) float part[2][8][64];
  hst[wave][lane] = 0.f;
  float creg = 0.f;                      // cell state: wave0 lanes<16
  __syncthreads();
  float xv = 0.f;
  if (wave == 0) xv = Xw[wg * 64 + lane];

#pragma unroll 1
  for (int t = 0; t < S_LEN; ++t) {
    if (t > 0) {
      const unsigned long long* sl = slots + ((t - 1) & 1) * HW + tid;
      unsigned long long v = poll2(sl, (unsigned)t);
      hst[wave][lane] = __uint_as_float((unsigned)v);
    }
    // next x-slice: issued AFTER the poll (so poll-entry vmcnt(0) doesn't
    // pay its latency); completes during dot+barrier+tail.
    float xn = 0.f;
    if (wave == 0) {
      int tt = (t + 1 < S_LEN) ? (t + 1) : t;
      xn = Xw[tt * (4 * HW) + wg * 64 + lane];
    }
    const float4* hp = (const float4*)hst[wave];
    float a0 = 0.f, a1 = 0.f, a2 = 0.f, a3 = 0.f;
#pragma unroll
    for (int j = 0; j < 4; ++j) {
      float4 h0 = hp[4*j+0], h1 = hp[4*j+1], h2 = hp[4*j+2], h3 = hp[4*j+3];
      float4 w0 = wreg[4*j+0], w1 = wreg[4*j+1], w2 = wreg[4*j+2], w3 = wreg[4*j+3];
      a0 += w0.x*h0.x + w0.y*h0.y + w0.z*h0.z + w0.w*h0.w;
      a1 += w1.x*h1.x + w1.y*h1.y + w1.z*h1.z + w1.w*h1.w;
      a2 += w2.x*h2.x + w2.y*h2.y + w2.z*h2.z + w2.w*h2.w;
      a3 += w3.x*h3.x + w3.y*h3.y + w3.z*h3.z + w3.w*h3.w;
    }
    const int par = t & 1;
    part[par][wave][lane] = (a0 + a1) + (a2 + a3);
    barrier_lds();
    if (wave == 0) {
      float z = (((part[par][0][lane] + part[par][1][lane]) +
                  (part[par][2][lane] + part[par][3][lane])) +
                 ((part[par][4][lane] + part[par][5][lane]) +
                  (part[par][6][lane] + part[par][7][lane]))) + xv;
      int u = lane & 15;
      float zi = __shfl(z, u,      64);
      float zf = __shfl(z, u + 16, 64);
      float zg = __shfl(z, u + 32, 64);
      float zo = __shfl(z, u + 48, 64);
      if (lane < 16) {
        float ig = fsigmoid(zi), fg = fsigmoid(zf), og = fsigmoid(zo);
        float gg = ftanh(zg);
        creg = fg * creg + ig * gg;
        float h = og * ftanh(creg);
        unsigned long long pv =
            (((unsigned long long)(unsigned)(t + 1)) << 32) |
            (unsigned long long)__float_as_uint(h);
        publish(slots + par * HW + wg * 16 + lane, pv);
        out[t * HW + wg * 16 + lane] = h;
      }
      xv = xn;
    }
  }
}

// ---------------------------------------------------------------------------
extern "C" void kernel_launch(void* const* d_in, const int* in_sizes, int n_in,
                              void* d_out, int out_size, void* d_ws, size_t ws_size,
                              hipStream_t stream) {
  const float* E_char = (const float*)d_in[0];
  const float* W_ih_r = (const float*)d_in[1];
  const float* W_hh_r = (const float*)d_in[2];
  const float* b_r    = (const float*)d_in[3];
  const float* W_lat  = (const float*)d_in[4];
  const float* b_lat  = (const float*)d_in[5];
  const float* E_word = (const float*)d_in[6];
  const float* W_ih_w = (const float*)d_in[7];
  const float* W_hh_w = (const float*)d_in[8];
  const float* b_w    = (const float*)d_in[9];
  const int* word_ids = (const int*)d_in[10];
  const int* char_ids = (const int*)d_in[11];

  char* ws = (char*)d_ws;
  float*              tableR = (float*)(ws + 0x000000);              // 100 KB
  int*                electC = (int*)(ws + 0x020000);
  int*                electW = (int*)(ws + 0x020100);
  unsigned long long* slotC  = (unsigned long long*)(ws + 0x030000); // 4 KB
  unsigned long long* slotW  = (unsigned long long*)(ws + 0x050000); // 8 KB
  float*              h_word = (float*)(ws + 0x100000);              // 4 MB
  float*              latent = (float*)(ws + 0x500000);              // 2 MB
  float*              WT     = (float*)(ws + 0x700000);              // 2 MB
  float*              bperm  = (float*)(ws + 0x900000);              // 8 KB
  float*              Xw     = (float*)(ws + 0xA00000);              // 32 MB
  float* out = (float*)d_out;

  hipLaunchKernelGGL(k_init,      dim3(1),      dim3(64),  0, stream,
                     electC, electW);
  hipLaunchKernelGGL(k_table,     dim3(ALPHA),  dim3(256), 0, stream,
                     E_char, W_ih_r, b_r, tableR);
  hipLaunchKernelGGL(k_permw,     dim3(2048),   dim3(256), 0, stream,
                     W_ih_w, b_w, WT, bperm);
  hipLaunchKernelGGL(k_char_lstm, dim3(GRIDC),  dim3(256), 0, stream,
                     char_ids, W_hh_r, tableR, slotC, electC, h_word);
  hipLaunchKernelGGL(k_latent,    dim3(S_LEN),  dim3(128), 0, stream,
                     h_word, W_lat, b_lat, latent);
  hipLaunchKernelGGL(k_xw,        dim3(128, 8), dim3(256), 0, stream,
                     E_word, word_ids, latent, WT, bperm, Xw);
  hipLaunchKernelGGL(k_word_lstm, dim3(GRIDW),  dim3(512), 0, stream,
                     W_hh_w, Xw, slotW, electW, out);
}

// Round 4
// 19730.135 us; speedup vs baseline: 1.3204x; 1.3204x over previous
//
#include <hip/hip_runtime.h>

// ============================================================================
// Two-level LSTM (char k-mer LSTM -> word LSTM), MI355X.
//
// R11: FUSED char+word pipeline. R7->R10 showed the cross-CU recurrence
// exchange has a ~2750 cyc/step floor invariant under protocol micro-opt
// (RMW vs load poll, replicas vs single copy, poll depth, weight residency).
// So this round overlaps the phases instead: char cluster (16 WGs, XCD C)
// and word cluster (32 WGs, XCD W) run CONCURRENTLY in one persistent
// kernel. h_word flows char->word as tagged slots (tag = word_index+1)
// via builtin agent-scope store/load -- the same primitive class the
// cross-XCD election has proven every round. Word steps cost ~1.3us but
// words arrive every ~4.6us -> the whole word LSTM + latent + x-projection
// hides in the slack; k_latent / k_xw / k_permw kernels are DELETED
// (their work moved into the word WGs' idle time).
//
// Election (deadlock-free, pigeonhole): arrivals counted per XCD. First
// XCD to 32 arrivals = word home (its 32 spinners become the 32 word
// workers -- they saturate the XCD's 32 CUs, so no later WG lands there).
// Non-home WGs: the 16th arrival (r==15) on a non-home XCD CASes char
// home; all candidates spin until char home resolves, then first 16 on
// that XCD take char roles, rest lose+exit. Progress: spinners hold CUs,
// losers free them; with 512 WGs total and word home capped at 32 live,
// >=480 WGs must run on non-home XCDs => some non-home XCD reaches 16
// arrivals => char home always resolves. No cycles: char never waits on
// word; word waits only on char's h_word stream.
//
// Char WGs are 512-thread blocks (kernel-wide block size); waves 4..7 are
// PARKED in a barrier-matched loop (one barrier_lds per step, same count
// as the worker waves) -- no reliance on exited-wave barrier semantics.
// The R10-proven char exchange (poll2 sc1 2-deep pipelined poll, agent
// store publish, parity double-buffer) is unchanged.
//
// Stale-tag safety across bench iterations: h_word slots are write-once
// per run (no parity), so k_clear zeroes all 1M slots before the fused
// kernel each launch. slotC/slotW keep the R4 ascending-overwrite
// argument (every slot rewritten each 2 steps before its tag recurs).
// ============================================================================

#define S_LEN 4096
#define TCH   16384
#define ALPHA 25
#define ECH   64
#define HR    256
#define DL    128
#define EW    128
#define HW    512
#define NWC   16           // char worker WGs
#define NWW   32           // word worker WGs
#define GRIDF 512          // fused kernel grid

static __device__ __forceinline__ float fsigmoid(float x) {
  x = fminf(fmaxf(x, -30.f), 30.f);
  return __builtin_amdgcn_rcpf(1.0f + __expf(-x));
}
static __device__ __forceinline__ float ftanh(float x) {
  x = fminf(fmaxf(x, -15.f), 15.f);
  float e = __expf(2.0f * x);
  return 1.0f - 2.0f * __builtin_amdgcn_rcpf(e + 1.0f);
}

static __device__ __forceinline__ void barrier_lds() {
  asm volatile("s_waitcnt lgkmcnt(0)\n\ts_barrier" ::: "memory");
}

// 2-deep pipelined coherent poll (R10-proven, intra-XCD hot path).
static __device__ __forceinline__ unsigned long long poll2(
    const unsigned long long* p, unsigned tgt) {
  unsigned long long a, b;
  asm volatile("s_waitcnt vmcnt(0)" ::: "memory");
  asm volatile("global_load_dwordx2 %0, %1, off sc1"
               : "=v"(a) : "v"(p) : "memory");
  for (;;) {
    asm volatile("global_load_dwordx2 %0, %1, off sc1"
                 : "=v"(b) : "v"(p) : "memory");
    asm volatile("s_waitcnt vmcnt(1)" : "+v"(a) :: "memory");
    __builtin_amdgcn_sched_barrier(0);
    if ((unsigned)(a >> 32) == tgt) break;
    asm volatile("global_load_dwordx2 %0, %1, off sc1"
                 : "=v"(a) : "v"(p) : "memory");
    asm volatile("s_waitcnt vmcnt(1)" : "+v"(b) :: "memory");
    __builtin_amdgcn_sched_barrier(0);
    if ((unsigned)(b >> 32) == tgt) { a = b; break; }
  }
  asm volatile("s_waitcnt vmcnt(0)" ::: "memory");  // drain dangling load
  return a;
}
// Publish: agent-scope atomic store (compiler-correct cache bits).
static __device__ __forceinline__ void publish(
    unsigned long long* p, unsigned long long v) {
  __hip_atomic_store(p, v, __ATOMIC_RELAXED, __HIP_MEMORY_SCOPE_AGENT);
}
// Cross-XCD tagged poll (h_word path; off the hot recurrence).
static __device__ __forceinline__ unsigned long long poll_agent(
    const unsigned long long* p, unsigned tgt) {
  unsigned long long v;
  do {
    v = __hip_atomic_load(p, __ATOMIC_RELAXED, __HIP_MEMORY_SCOPE_AGENT);
  } while ((unsigned)(v >> 32) != tgt);
  return v;
}

// Two-cluster election. Returns: 0..31 word role, 64..79 char role, -1 loser.
static __device__ __forceinline__ int elect2(int* el) {
  unsigned xcd;
  asm volatile("s_getreg_b32 %0, hwreg(HW_REG_XCC_ID)" : "=s"(xcd));
  xcd &= 7u;
  int r = __hip_atomic_fetch_add(&el[xcd], 1, __ATOMIC_RELAXED,
                                 __HIP_MEMORY_SCOPE_AGENT);
  if (r == NWW - 1) {                       // 32nd arrival: claim word home
    int exp = -1;
    __hip_atomic_compare_exchange_strong(&el[8], &exp, (int)xcd,
        __ATOMIC_RELAXED, __ATOMIC_RELAXED, __HIP_MEMORY_SCOPE_AGENT);
  }
  int w;
  while ((w = __hip_atomic_load(&el[8], __ATOMIC_RELAXED,
                                __HIP_MEMORY_SCOPE_AGENT)) < 0) {}
  if ((int)xcd == w) {
    int rr = __hip_atomic_fetch_add(&el[9], 1, __ATOMIC_RELAXED,
                                    __HIP_MEMORY_SCOPE_AGENT);
    return (rr < NWW) ? rr : -1;
  }
  if (r == NWC - 1) {                       // 16th arrival on non-home XCD
    int exp = -1;
    __hip_atomic_compare_exchange_strong(&el[10], &exp, (int)xcd,
        __ATOMIC_RELAXED, __ATOMIC_RELAXED, __HIP_MEMORY_SCOPE_AGENT);
  }
  int c;
  while ((c = __hip_atomic_load(&el[10], __ATOMIC_RELAXED,
                                __HIP_MEMORY_SCOPE_AGENT)) < 0) {}
  if ((int)xcd != c) return -1;
  int rc = __hip_atomic_fetch_add(&el[11], 1, __ATOMIC_RELAXED,
                                  __HIP_MEMORY_SCOPE_AGENT);
  return (rc < NWC) ? (64 + rc) : -1;
}

__global__ void k_init(int* el) {
  int t = threadIdx.x;
  if (t < 12) el[t] = (t == 8 || t == 10) ? -1 : 0;
}

// Clear the 1M h_word tagged slots (8 MB) -- kills stale tags between
// bench iterations (slots are write-once per run).
__global__ void k_clear(unsigned long long* p) {
  p[blockIdx.x * 256 + threadIdx.x] = 0ull;
}

// ---------------------------------------------------------------------------
// K1a: char gate-input table: table[a][row] = b_r[row] + E_char[a,:]·W_ih_r[row,:]
// ---------------------------------------------------------------------------
__global__ void k_table(const float* __restrict__ Ec, const float* __restrict__ Wih,
                        const float* __restrict__ br, float* __restrict__ table) {
  __shared__ __align__(16) float e[ECH];
  int a = blockIdx.x, tid = threadIdx.x;
  if (tid < ECH) e[tid] = Ec[a * ECH + tid];
  __syncthreads();
  for (int row = tid; row < 4 * HR; row += 256) {
    const float4* w = (const float4*)(Wih + row * ECH);
    const float4* e4 = (const float4*)e;
    float acc = 0.f;
#pragma unroll
    for (int j = 0; j < ECH / 4; ++j) {
      float4 wv = w[j], ev = e4[j];
      acc += wv.x * ev.x + wv.y * ev.y + wv.z * ev.z + wv.w * ev.w;
    }
    table[a * (4 * HR) + row] = acc + br[row];
  }
}

// ---------------------------------------------------------------------------
// Char worker path: R10's proven loop; waves 4..7 parked (barrier-matched).
// h_word published as tagged slots (tag = word_index+1) for the word cluster.
// ---------------------------------------------------------------------------
static __device__ __forceinline__ void char_path(
    int wg, const int* __restrict__ char_ids, const float* __restrict__ Whh,
    const float* __restrict__ table, unsigned long long* __restrict__ slots,
    unsigned long long* __restrict__ hw)
{
  const int tid = threadIdx.x;
  const int wave = tid >> 6, lane = tid & 63;

  __shared__ __align__(16) float tab[ALPHA * 64];
  __shared__ __align__(16) float hst[4][64];
  __shared__ __align__(16) float part[2][4][64];
  for (int i = tid; i < ALPHA * 64; i += 512) {
    int chh = i >> 6, r = i & 63;
    int Rr = (r >> 4) * HR + wg * 16 + (r & 15);
    tab[i] = table[chh * (4 * HR) + Rr];
  }

  float4 wreg[16];
  if (wave < 4) {
    const int R = (lane >> 4) * HR + wg * 16 + (lane & 15);
    const float4* wp = (const float4*)(Whh + R * HR + wave * 64);
#pragma unroll
    for (int j = 0; j < 16; ++j) wreg[j] = wp[j];
    hst[wave][lane] = 0.f;
  }
  float creg = 0.f;                      // cell state: wave0 lanes<16
  __syncthreads();

  if (wave >= 4) {                       // parked waves: barrier-matched idle
#pragma unroll 1
    for (int t = 0; t < TCH; ++t) barrier_lds();
    return;
  }

  int ch = char_ids[0];
#pragma unroll 1
  for (int t = 0; t < TCH; ++t) {
    float tabv = 0.f;
    if (wave == 0) tabv = tab[ch * 64 + lane];
    if (t > 0) {
      const unsigned long long* sl = slots + ((t - 1) & 1) * HR + tid;
      unsigned long long v = poll2(sl, (unsigned)t);
      hst[wave][lane] = __uint_as_float((unsigned)v);
    }
    int chn = (t + 1 < TCH) ? char_ids[t + 1] : 0;
    const float4* hp = (const float4*)hst[wave];
    float a0 = 0.f, a1 = 0.f, a2 = 0.f, a3 = 0.f;
#pragma unroll
    for (int j = 0; j < 4; ++j) {
      float4 h0 = hp[4*j+0], h1 = hp[4*j+1], h2 = hp[4*j+2], h3 = hp[4*j+3];
      float4 w0 = wreg[4*j+0], w1 = wreg[4*j+1], w2 = wreg[4*j+2], w3 = wreg[4*j+3];
      a0 += w0.x*h0.x + w0.y*h0.y + w0.z*h0.z + w0.w*h0.w;
      a1 += w1.x*h1.x + w1.y*h1.y + w1.z*h1.z + w1.w*h1.w;
      a2 += w2.x*h2.x + w2.y*h2.y + w2.z*h2.z + w2.w*h2.w;
      a3 += w3.x*h3.x + w3.y*h3.y + w3.z*h3.z + w3.w*h3.w;
    }
    const int par = t & 1;
    part[par][wave][lane] = (a0 + a1) + (a2 + a3);
    barrier_lds();                       // single barrier per step
    if (wave == 0) {
      float z = ((part[par][0][lane] + part[par][1][lane]) +
                 (part[par][2][lane] + part[par][3][lane])) + tabv;
      int u = lane & 15;
      float zi = __shfl(z, u,      64);
      float zf = __shfl(z, u + 16, 64);
      float zg = __shfl(z, u + 32, 64);
      float zo = __shfl(z, u + 48, 64);
      if (lane < 16) {
        float ig = fsigmoid(zi), fg = fsigmoid(zf), og = fsigmoid(zo);
        float gg = ftanh(zg);
        creg = fg * creg + ig * gg;
        float h = og * ftanh(creg);
        unsigned long long pv =
            (((unsigned long long)(unsigned)(t + 1)) << 32) |
            (unsigned long long)__float_as_uint(h);
        publish(slots + par * HR + wg * 16 + lane, pv);
        if ((t & 3) == 3) {              // tagged h_word for word cluster
          unsigned long long hv =
              (((unsigned long long)(unsigned)((t >> 2) + 1)) << 32) |
              (unsigned long long)__float_as_uint(h);
          publish(hw + (t >> 2) * HR + wg * 16 + lane, hv);
        }
      }
    }
    ch = chn;
  }
}

// ---------------------------------------------------------------------------
// Word worker path. Per step t (budget ~4.6us, work ~1.5us):
//  1. prefetch we -> xsh[0:128); poll tagged h_word[t] -> hwsh     [barrier]
//  2. latent = tanh(W_lat·hw + b_lat) -> xsh[128:256)              [barrier]
//  3. poll slotW for h(t-1); z = Whh·h + Wx·x + b (x-partials folded into
//     the existing per-wave part[] reduce)                         [barrier]
//  4. wave0: reduce, gates, publish h(t), write out[t].
// ---------------------------------------------------------------------------
static __device__ __forceinline__ void word_path(
    int wg, const float* __restrict__ Whh, const float* __restrict__ Wihw,
    const float* __restrict__ bww, const float* __restrict__ Wlat,
    const float* __restrict__ blat, const float* __restrict__ Ew,
    const int* __restrict__ wid, const unsigned long long* __restrict__ hw,
    unsigned long long* __restrict__ slots, float* __restrict__ out)
{
  const int tid = threadIdx.x;
  const int wave = tid >> 6, lane = tid & 63;
  const int R = (lane >> 4) * HW + wg * 16 + (lane & 15);

  float4 wreg[16];                       // Whh rows, k in [64w, 64w+64)
  {
    const float4* wp = (const float4*)(Whh + R * HW + wave * 64);
#pragma unroll
    for (int j = 0; j < 16; ++j) wreg[j] = wp[j];
  }
  float4 xwr[8];                         // W_ih_w rows, k in [32w, 32w+32)
  {
    const float4* xp = (const float4*)(Wihw + R * (EW + DL) + wave * 32);
#pragma unroll
    for (int j = 0; j < 8; ++j) xwr[j] = xp[j];
  }
  const float bw = bww[R];
  float4 wl[16];                         // W_lat row d, k-seg 64*(tid&3)
  {
    const float4* lp =
        (const float4*)(Wlat + (tid >> 2) * HR + (tid & 3) * 64);
#pragma unroll
    for (int j = 0; j < 16; ++j) wl[j] = lp[j];
  }
  const float bl = blat[tid >> 2];

  __shared__ __align__(16) float hwsh[HR];
  __shared__ __align__(16) float xsh[EW + DL];
  __shared__ __align__(16) float hst[8][64];
  __shared__ __align__(16) float part[2][8][64];
  hst[wave][lane] = 0.f;
  float creg = 0.f;                      // cell state: wave0 lanes<16
  __syncthreads();

#pragma unroll 1
  for (int t = 0; t < S_LEN; ++t) {
    int wt = wid[t];
    if (tid < EW) xsh[tid] = Ew[wt * EW + tid];      // we (overlaps poll)
    if (tid < HR) {                                  // tagged h_word poll
      unsigned long long v = poll_agent(hw + t * HR + tid, (unsigned)(t + 1));
      hwsh[tid] = __uint_as_float((unsigned)v);
    }
    barrier_lds();
    // latent: thread (d=tid>>2, kq=tid&3), 64 MACs, 4-lane shfl reduce
    {
      const float4* h4 = ((const float4*)hwsh) + (tid & 3) * 16;
      float la = 0.f;
#pragma unroll
      for (int j = 0; j < 16; ++j) {
        float4 hv = h4[j], wv = wl[j];
        la += wv.x*hv.x + wv.y*hv.y + wv.z*hv.z + wv.w*hv.w;
      }
      la += __shfl_xor(la, 1, 64);
      la += __shfl_xor(la, 2, 64);
      if ((tid & 3) == 0) xsh[EW + (tid >> 2)] = ftanh(la + bl);
    }
    barrier_lds();
    if (t > 0) {
      const unsigned long long* sl = slots + ((t - 1) & 1) * HW + tid;
      unsigned long long v = poll2(sl, (unsigned)t);
      hst[wave][lane] = __uint_as_float((unsigned)v);
    }
    const float4* hp = (const float4*)hst[wave];
    float a0 = 0.f, a1 = 0.f, a2 = 0.f, a3 = 0.f;
#pragma unroll
    for (int j = 0; j < 4; ++j) {
      float4 h0 = hp[4*j+0], h1 = hp[4*j+1], h2 = hp[4*j+2], h3 = hp[4*j+3];
      float4 w0 = wreg[4*j+0], w1 = wreg[4*j+1], w2 = wreg[4*j+2], w3 = wreg[4*j+3];
      a0 += w0.x*h0.x + w0.y*h0.y + w0.z*h0.z + w0.w*h0.w;
      a1 += w1.x*h1.x + w1.y*h1.y + w1.z*h1.z + w1.w*h1.w;
      a2 += w2.x*h2.x + w2.y*h2.y + w2.z*h2.z + w2.w*h2.w;
      a3 += w3.x*h3.x + w3.y*h3.y + w3.z*h3.z + w3.w*h3.w;
    }
    float xd = (wave == 0) ? bw : 0.f;   // x-projection partial (+bias once)
    {
      const float4* xx = ((const float4*)xsh) + wave * 8;
#pragma unroll
      for (int j = 0; j < 8; ++j) {
        float4 xv4 = xx[j], wv = xwr[j];
        xd += wv.x*xv4.x + wv.y*xv4.y + wv.z*xv4.z + wv.w*xv4.w;
      }
    }
    const int par = t & 1;
    part[par][wave][lane] = ((a0 + a1) + (a2 + a3)) + xd;
    barrier_lds();
    if (wave == 0) {
      float z = (((part[par][0][lane] + part[par][1][lane]) +
                  (part[par][2][lane] + part[par][3][lane])) +
                 ((part[par][4][lane] + part[par][5][lane]) +
                  (part[par][6][lane] + part[par][7][lane])));
      int u = lane & 15;
      float zi = __shfl(z, u,      64);
      float zf = __shfl(z, u + 16, 64);
      float zg = __shfl(z, u + 32, 64);
      float zo = __shfl(z, u + 48, 64);
      if (lane < 16) {
        float ig = fsigmoid(zi), fg = fsigmoid(zf), og = fsigmoid(zo);
        float gg = ftanh(zg);
        creg = fg * creg + ig * gg;
        float h = og * ftanh(creg);
        unsigned long long pv =
            (((unsigned long long)(unsigned)(t + 1)) << 32) |
            (unsigned long long)__float_as_uint(h);
        publish(slots + par * HW + wg * 16 + lane, pv);
        out[t * HW + wg * 16 + lane] = h;
      }
    }
  }
}

// ---------------------------------------------------------------------------
__global__ __attribute__((amdgpu_flat_work_group_size(512, 512),
                          amdgpu_waves_per_eu(2, 2)))
void k_fused(
    const int* __restrict__ char_ids, const float* __restrict__ Whh_r,
    const float* __restrict__ table, unsigned long long* __restrict__ slotC,
    unsigned long long* __restrict__ hw,
    const float* __restrict__ Whh_w, const float* __restrict__ Wihw,
    const float* __restrict__ b_w, const float* __restrict__ Wlat,
    const float* __restrict__ blat, const float* __restrict__ Ew,
    const int* __restrict__ wid, unsigned long long* __restrict__ slotW,
    int* __restrict__ elect, float* __restrict__ out)
{
  __shared__ int role_sh;
  if (threadIdx.x == 0) role_sh = elect2(elect);
  __syncthreads();
  const int role = role_sh;
  if (role < 0) return;
  if (role >= 64)
    char_path(role - 64, char_ids, Whh_r, table, slotC, hw);
  else
    word_path(role, Whh_w, Wihw, b_w, Wlat, blat, Ew, wid, hw, slotW, out);
}

// ---------------------------------------------------------------------------
extern "C" void kernel_launch(void* const* d_in, const int* in_sizes, int n_in,
                              void* d_out, int out_size, void* d_ws, size_t ws_size,
                              hipStream_t stream) {
  const float* E_char = (const float*)d_in[0];
  const float* W_ih_r = (const float*)d_in[1];
  const float* W_hh_r = (const float*)d_in[2];
  const float* b_r    = (const float*)d_in[3];
  const float* W_lat  = (const float*)d_in[4];
  const float* b_lat  = (const float*)d_in[5];
  const float* E_word = (const float*)d_in[6];
  const float* W_ih_w = (const float*)d_in[7];
  const float* W_hh_w = (const float*)d_in[8];
  const float* b_w    = (const float*)d_in[9];
  const int* word_ids = (const int*)d_in[10];
  const int* char_ids = (const int*)d_in[11];

  char* ws = (char*)d_ws;
  float*              tableR = (float*)(ws + 0x000000);              // 100 KB
  int*                elect  = (int*)(ws + 0x020000);                // 48 B
  unsigned long long* slotC  = (unsigned long long*)(ws + 0x030000); // 4 KB
  unsigned long long* slotW  = (unsigned long long*)(ws + 0x040000); // 8 KB
  unsigned long long* hw     = (unsigned long long*)(ws + 0x100000); // 8 MB
  float* out = (float*)d_out;

  hipLaunchKernelGGL(k_init,  dim3(1),     dim3(64),  0, stream, elect);
  hipLaunchKernelGGL(k_clear, dim3(4096),  dim3(256), 0, stream, hw);
  hipLaunchKernelGGL(k_table, dim3(ALPHA), dim3(256), 0, stream,
                     E_char, W_ih_r, b_r, tableR);
  hipLaunchKernelGGL(k_fused, dim3(GRIDF), dim3(512), 0, stream,
                     char_ids, W_hh_r, tableR, slotC, hw,
                     W_hh_w, W_ih_w, b_w, W_lat, b_lat, E_word,
                     word_ids, slotW, elect, out);
}